// Round 9
// baseline (596.679 us; speedup 1.0000x reference)
//
#include <hip/hip_runtime.h>
#include <stdint.h>

typedef _Float16 f16;
typedef _Float16 f16x8 __attribute__((ext_vector_type(8)));
typedef _Float16 f16x4 __attribute__((ext_vector_type(4)));
typedef float    f32x4 __attribute__((ext_vector_type(4)));

#define SEQ   2048
#define EDIM  2048
#define NHQ   32
#define NHKV  8
#define DHEAD 64
#define KVD   512
#define NB    2
#define NTOK  (NB*SEQ)
#define QKVN  3072              // packed Q|K|V projection width
#define SCALE 0.1803368801111204f   // log2(e)/8

__device__ __forceinline__ f32x4 mfma16(f16x8 a, f16x8 b, f32x4 c) {
  return __builtin_amdgcn_mfma_f32_16x16x32_f16(a, b, c, 0, 0, 0);
}

__device__ __forceinline__ void gload_lds16(const void* g, void* l) {
  __builtin_amdgcn_global_load_lds(
      (const __attribute__((address_space(1))) void*)g,
      (__attribute__((address_space(3))) void*)l, 16, 0, 0);
}

// ---------------- fused prep: cvt3 (blocks 0..24575) + tconv EDIMxEDIM pair
// (24576..32767) + tconv EDIMxKVD pair (32768..34815), one launch ----------------
__global__ __launch_bounds__(256) void k_prep(
    const float* __restrict__ q, const float* __restrict__ k,
    const float* __restrict__ v, f16* __restrict__ d3,
    const float* __restrict__ Wq, const float* __restrict__ Wo,
    f16* __restrict__ wqT, f16* __restrict__ woT,
    const float* __restrict__ Wk, const float* __restrict__ Wv,
    f16* __restrict__ wkT, f16* __restrict__ wvT)
{
  __shared__ float t[32][33];
  const int blk = blockIdx.x;
  if (blk < 24576) {                       // convert q,k,v f32 -> f16
    int i = blk * 256 + threadIdx.x;
    int tt = i >> 21, j = i & ((1 << 21) - 1);
    const float* s = tt == 0 ? q : (tt == 1 ? k : v);
    float4 vv = reinterpret_cast<const float4*>(s)[j];
    f16x4 h;
    h[0] = (f16)vv.x; h[1] = (f16)vv.y; h[2] = (f16)vv.z; h[3] = (f16)vv.w;
    reinterpret_cast<f16x4*>(d3)[i] = h;
    return;
  }
  const float* s; f16* d; int C, tr, tc;
  if (blk < 32768) {                       // Wq / Wo transpose-convert
    int bb = blk - 24576;
    int z = bb >> 12; bb &= 4095;
    tr = bb >> 6; tc = bb & 63;
    s = z ? Wo : Wq; d = z ? woT : wqT; C = EDIM;
  } else {                                 // Wk / Wv transpose-convert
    int bb = blk - 32768;
    int z = bb >> 10; bb &= 1023;
    tr = bb >> 4; tc = bb & 15;
    s = z ? Wv : Wk; d = z ? wvT : wkT; C = KVD;
  }
  int lr = threadIdx.x >> 3, lc = (threadIdx.x & 7) << 2;
  float4 vv = *reinterpret_cast<const float4*>(&s[(size_t)(tr*32+lr)*C + tc*32 + lc]);
  t[lr][lc+0] = vv.x; t[lr][lc+1] = vv.y; t[lr][lc+2] = vv.z; t[lr][lc+3] = vv.w;
  __syncthreads();
  f16x4 h;
  h[0] = (f16)t[lc+0][lr];
  h[1] = (f16)t[lc+1][lr];
  h[2] = (f16)t[lc+2][lr];
  h[3] = (f16)t[lc+3][lr];
  *reinterpret_cast<f16x4*>(&d[(size_t)(tc*32+lr)*EDIM + tr*32 + lc]) = h;
}

// ------- transpose V slice of QKVp: [4096][3072](cols 2560+) -> Vt [16][64][2048] -------
__global__ __launch_bounds__(256) void k_trv(const f16* __restrict__ qkv,
                                             f16* __restrict__ dst) {
  __shared__ f16 t[64][68];
  int bh = blockIdx.x;            // b*8 + hkv
  int st = blockIdx.y;            // s tile (64)
  int b = bh >> 3, h = bh & 7;
  #pragma unroll
  for (int i = 0; i < 4; ++i) {
    int sl = i*16 + (threadIdx.x >> 4);
    int d4 = (threadIdx.x & 15) * 4;
    *(f16x4*)&t[sl][d4] =
        *(const f16x4*)&qkv[(size_t)(b*SEQ + st*64 + sl)*QKVN + 2560 + h*DHEAD + d4];
  }
  __syncthreads();
  #pragma unroll
  for (int i = 0; i < 4; ++i) {
    int dl = i*16 + (threadIdx.x >> 4);
    int s4 = (threadIdx.x & 15) * 4;
    f16x4 v;
    v[0] = t[s4+0][dl]; v[1] = t[s4+1][dl]; v[2] = t[s4+2][dl]; v[3] = t[s4+3][dl];
    *(f16x4*)&dst[(size_t)(bh*DHEAD + dl)*SEQ + st*64 + s4] = v;
  }
}

// ------- fused QKV projection: QKVp[4096][3072] = [q16|k16|v16] @ Wt^T + bias -------
__global__ __launch_bounds__(256) void k_gemm_qkv(
    const f16* __restrict__ Abase,   // q16; k16,v16 follow contiguously
    const f16* __restrict__ Wt,
    const float* __restrict__ bq, const float* __restrict__ bk,
    const float* __restrict__ bv,
    f16* __restrict__ Cout)
{
  const int flat = blockIdx.y * gridDim.x + blockIdx.x;   // 0..767
  const int xcd = flat & 7, idx = flat >> 3;              // idx 0..95
  const int tn = xcd*3 + (idx % 3);
  const int tm = idx / 3;
  const int sel = (tn >= 16) + (tn >= 20);
  const f16* A = Abase + (size_t)sel*NTOK*EDIM;
  const float* bias = sel == 0 ? bq : (sel == 1 ? bk : bv);
  const int coff = sel == 0 ? 0 : (sel == 1 ? 2048 : 2560);

  __shared__ f16 sA[128*64];
  __shared__ f16 sB[128*64];
  const int tid  = threadIdx.x;
  const int lane = tid & 63, wv = tid >> 6;
  const int wm = wv >> 1, wn = wv & 1;
  const int l15 = lane & 15, lhi = lane >> 4;

  const f32x4 zz = {0.f, 0.f, 0.f, 0.f};
  f32x4 acc[4][4];
  #pragma unroll
  for (int m = 0; m < 4; ++m)
    #pragma unroll
    for (int n = 0; n < 4; ++n) acc[m][n] = zz;

  const f16* gsrc[8];
  f16* ldst[8];
  #pragma unroll
  for (int i = 0; i < 8; ++i) {
    int u = wv*8 + i;
    int r  = (u & 15)*8 + (lane >> 3);
    int cb = ((lane & 7) << 4) ^ ((r & 7) << 4);
    if (u < 16) {
      gsrc[i] = A  + (size_t)(tm*128 + r)*EDIM + (cb >> 1);
      ldst[i] = sA + u*512;
    } else {
      gsrc[i] = Wt + (size_t)(tn*128 + r)*EDIM + (cb >> 1);
      ldst[i] = sB + (u - 16)*512;
    }
  }

  int aoff[2][4], boff[2][4];
  #pragma unroll
  for (int ks = 0; ks < 2; ++ks)
    #pragma unroll
    for (int m = 0; m < 4; ++m) {
      int ra = wm*64 + m*16 + l15;
      aoff[ks][m] = ra*128 + ((ks*64 + (lhi << 4)) ^ ((ra & 7) << 4));
      int rb = wn*64 + m*16 + l15;
      boff[ks][m] = rb*128 + ((ks*64 + (lhi << 4)) ^ ((rb & 7) << 4));
    }

  for (int kb = 0; kb < EDIM/64; ++kb) {
    #pragma unroll
    for (int i = 0; i < 8; ++i)
      gload_lds16(gsrc[i] + kb*64, ldst[i]);
    __syncthreads();
    #pragma unroll
    for (int ks = 0; ks < 2; ++ks) {
      f16x8 af[4], bf[4];
      #pragma unroll
      for (int m = 0; m < 4; ++m)
        af[m] = *(const f16x8*)((const char*)sA + aoff[ks][m]);
      #pragma unroll
      for (int n = 0; n < 4; ++n)
        bf[n] = *(const f16x8*)((const char*)sB + boff[ks][n]);
      #pragma unroll
      for (int m = 0; m < 4; ++m)
        #pragma unroll
        for (int n = 0; n < 4; ++n)
          acc[m][n] = mfma16(af[m], bf[n], acc[m][n]);
    }
    __syncthreads();
  }

  float bcol[4];
  #pragma unroll
  for (int n = 0; n < 4; ++n)
    bcol[n] = bias[tn*128 + wn*64 + n*16 + l15 - coff];
  #pragma unroll
  for (int m = 0; m < 4; ++m)
    #pragma unroll
    for (int n = 0; n < 4; ++n)
      #pragma unroll
      for (int r = 0; r < 4; ++r) {
        int row = tm*128 + wm*64 + m*16 + lhi*4 + r;
        int col = tn*128 + wn*64 + n*16 + l15;
        Cout[(size_t)row*QKVN + col] = (f16)(acc[m][n][r] + bcol[n]);
      }
}

// ---------------- GEMM (out-proj): C[M,N] f32 = A[M,K] * Bt[N,K]^T + bias ----------------
__global__ __launch_bounds__(256) void k_gemm(
    const f16* __restrict__ A, const f16* __restrict__ Bt,
    const float* __restrict__ bias, float* __restrict__ Cout,
    int M, int N, int K)
{
  const int flat = blockIdx.y * gridDim.x + blockIdx.x;   // 0..511
  const int xcd = flat & 7, idx = flat >> 3;              // idx 0..63
  const int tn = xcd*2 + (idx & 1);
  const int tm = idx >> 1;

  __shared__ f16 sA[128*64];
  __shared__ f16 sB[128*64];
  const int tid  = threadIdx.x;
  const int lane = tid & 63, wv = tid >> 6;
  const int wm = wv >> 1, wn = wv & 1;
  const int l15 = lane & 15, lhi = lane >> 4;

  const f32x4 zz = {0.f, 0.f, 0.f, 0.f};
  f32x4 acc[4][4];
  #pragma unroll
  for (int m = 0; m < 4; ++m)
    #pragma unroll
    for (int n = 0; n < 4; ++n) acc[m][n] = zz;

  const f16* gsrc[8];
  f16* ldst[8];
  #pragma unroll
  for (int i = 0; i < 8; ++i) {
    int u = wv*8 + i;
    int r  = (u & 15)*8 + (lane >> 3);
    int cb = ((lane & 7) << 4) ^ ((r & 7) << 4);
    if (u < 16) {
      gsrc[i] = A  + (size_t)(tm*128 + r)*K + (cb >> 1);
      ldst[i] = sA + u*512;
    } else {
      gsrc[i] = Bt + (size_t)(tn*128 + r)*K + (cb >> 1);
      ldst[i] = sB + (u - 16)*512;
    }
  }

  int aoff[2][4], boff[2][4];
  #pragma unroll
  for (int ks = 0; ks < 2; ++ks)
    #pragma unroll
    for (int m = 0; m < 4; ++m) {
      int ra = wm*64 + m*16 + l15;
      aoff[ks][m] = ra*128 + ((ks*64 + (lhi << 4)) ^ ((ra & 7) << 4));
      int rb = wn*64 + m*16 + l15;
      boff[ks][m] = rb*128 + ((ks*64 + (lhi << 4)) ^ ((rb & 7) << 4));
    }

  const int nkb = K >> 6;
  for (int kb = 0; kb < nkb; ++kb) {
    #pragma unroll
    for (int i = 0; i < 8; ++i)
      gload_lds16(gsrc[i] + kb*64, ldst[i]);
    __syncthreads();
    #pragma unroll
    for (int ks = 0; ks < 2; ++ks) {
      f16x8 af[4], bf[4];
      #pragma unroll
      for (int m = 0; m < 4; ++m)
        af[m] = *(const f16x8*)((const char*)sA + aoff[ks][m]);
      #pragma unroll
      for (int n = 0; n < 4; ++n)
        bf[n] = *(const f16x8*)((const char*)sB + boff[ks][n]);
      #pragma unroll
      for (int m = 0; m < 4; ++m)
        #pragma unroll
        for (int n = 0; n < 4; ++n)
          acc[m][n] = mfma16(af[m], bf[n], acc[m][n]);
    }
    __syncthreads();
  }

  float bcol[4];
  #pragma unroll
  for (int n = 0; n < 4; ++n)
    bcol[n] = bias[tn*128 + wn*64 + n*16 + l15];
  #pragma unroll
  for (int m = 0; m < 4; ++m)
    #pragma unroll
    for (int n = 0; n < 4; ++n)
      #pragma unroll
      for (int r = 0; r < 4; ++r) {
        int row = tm*128 + wm*64 + m*16 + lhi*4 + r;
        int col = tn*128 + wn*64 + n*16 + l15;
        Cout[(size_t)row*N + col] = acc[m][n][r] + bcol[n];
      }
}

// ---------------- fused GQA attention ----------------
// Pass A: barrier-free — K fragments read directly from global (K panel is
// L2-resident per XCD; lesson #7). Pass B unchanged (round-5 structure).
__global__ __launch_bounds__(256) void k_attn(
    const f16* __restrict__ QKV,  // [4096][3072]: Q | K | V
    const f16* __restrict__ Vt,   // [16][64][2048]
    float* __restrict__ wout,     // [2][32][2048][2048]
    f16* __restrict__ AO)         // [4096][2048]
{
  __shared__ f16 sK[2][64*64];
  __shared__ f16 sV[2][64*64];
  __shared__ f16 sW[4][16*64];
  const int tid = threadIdx.x, lane = tid & 63, wv = tid >> 6;
  const int bid = (blockIdx.x & 7) * 256 + (blockIdx.x >> 3);  // 2048 % 8 == 0
  const int b = bid >> 10, h = (bid >> 5) & 31, qb = bid & 31;
  const int hk = h >> 2;
  const int l15 = lane & 15, lhi = lane >> 4;
  const int rloc = (lane >> 3) & 7, chk = lane & 7;
  const int csw = (chk ^ rloc) * 8;
  const int sw  = (l15 & 7) << 4;
  const int qrow0 = qb*64 + wv*16;
  const f32x4 zz = {0.f, 0.f, 0.f, 0.f};

  f16x8 qf[2];
  #pragma unroll
  for (int ks = 0; ks < 2; ++ks)
    qf[ks] = *(const f16x8*)&QKV[(size_t)(b*SEQ + qrow0 + l15)*QKVN
                                 + h*DHEAD + ks*32 + lhi*8];

  const f16* Kb = QKV + 2048 + (size_t)(b*SEQ)*QKVN + hk*DHEAD;
  const f16* Vb = Vt + (size_t)((b*NHKV + hk)*DHEAD)*SEQ;

  // ---- pass A: barrier-free denominator; K direct from global (L2-hot) ----
  float lsum = 0.f;
  for (int k0 = 0; k0 < SEQ; k0 += 16) {
    f16x8 kf0 = *(const f16x8*)&Kb[(size_t)(k0 + l15)*QKVN + lhi*8];
    f16x8 kf1 = *(const f16x8*)&Kb[(size_t)(k0 + l15)*QKVN + 32 + lhi*8];
    f32x4 s = zz;
    s = mfma16(kf0, qf[0], s);       // swapped: row=k, col=q(l15)
    s = mfma16(kf1, qf[1], s);
    #pragma unroll
    for (int r = 0; r < 4; ++r)
      lsum += __builtin_amdgcn_exp2f(s[r] * SCALE);
  }
  float den = lsum;
  den += __shfl_xor(den, 16);
  den += __shfl_xor(den, 32);
  const float rinv = __builtin_amdgcn_rcpf(den);

  // ---- pass B ----
  f32x4 o[4];
  #pragma unroll
  for (int dt = 0; dt < 4; ++dt) o[dt] = zz;

  f16* swv = &sW[wv][0];
  float* wrow = wout + (size_t)((b*NHQ + h)*SEQ + qrow0)*SEQ;

  {
    #pragma unroll
    for (int i = 0; i < 2; ++i) {
      int u = wv*2 + i;
      gload_lds16(Kb + (size_t)(u*8 + rloc)*QKVN + csw, &sK[0][u*512]);
      gload_lds16(Vb + (size_t)(u*8 + rloc)*SEQ + csw, &sV[0][u*512]);
    }
    __syncthreads();
    int buf = 0;
    for (int kb = 0; kb < SEQ/64; ++kb) {
      if (kb < SEQ/64 - 1) {
        #pragma unroll
        for (int i = 0; i < 2; ++i) {
          int u = wv*2 + i;
          gload_lds16(Kb + (size_t)((kb+1)*64 + u*8 + rloc)*QKVN + csw, &sK[buf^1][u*512]);
          gload_lds16(Vb + (size_t)(u*8 + rloc)*SEQ + (kb+1)*64 + csw, &sV[buf^1][u*512]);
        }
      }
      __builtin_amdgcn_sched_barrier(0);
      #pragma unroll
      for (int kt = 0; kt < 4; ++kt) {
        const char* kbase = (const char*)&sK[buf][0] + (kt*16 + l15)*128;
        f16x8 kf0 = *(const f16x8*)(kbase + ((lhi*16) ^ sw));
        f16x8 kf1 = *(const f16x8*)(kbase + ((64 + lhi*16) ^ sw));
        f32x4 s = zz;
        s = mfma16(kf0, qf[0], s);
        s = mfma16(kf1, qf[1], s);
        f32x4 wvec;
        f16x4 wh;
        #pragma unroll
        for (int r = 0; r < 4; ++r) {
          float wgt = __builtin_amdgcn_exp2f(s[r] * SCALE) * rinv;
          wvec[r] = wgt;
          wh[r] = (f16)wgt;
        }
        __builtin_nontemporal_store(wvec,
            (f32x4*)(wrow + (size_t)l15*SEQ + kb*64 + kt*16 + lhi*4));
        *(f16x4*)((char*)swv + l15*128 + ((kt*32 + lhi*8) ^ sw)) = wh;
      }
      #pragma unroll
      for (int ks = 0; ks < 2; ++ks) {
        f16x8 af = *(const f16x8*)((const char*)swv + l15*128 + ((ks*64 + lhi*16) ^ sw));
        #pragma unroll
        for (int dt = 0; dt < 4; ++dt) {
          const char* vbase = (const char*)&sV[buf][0] + (dt*16 + l15)*128;
          f16x8 vf = *(const f16x8*)(vbase + ((ks*64 + lhi*16) ^ sw));
          o[dt] = mfma16(af, vf, o[dt]);
        }
      }
      asm volatile("s_waitcnt vmcnt(4)" ::: "memory");
      __builtin_amdgcn_s_barrier();
      __builtin_amdgcn_sched_barrier(0);
      buf ^= 1;
    }
  }

  #pragma unroll
  for (int dt = 0; dt < 4; ++dt)
    #pragma unroll
    for (int r = 0; r < 4; ++r)
      AO[(size_t)(b*SEQ + qrow0 + lhi*4 + r)*EDIM + h*DHEAD + dt*16 + l15]
          = (f16)o[dt][r];
}

// ---------------- launch ----------------
extern "C" void kernel_launch(void* const* d_in, const int* in_sizes, int n_in,
                              void* d_out, int out_size, void* d_ws, size_t ws_size,
                              hipStream_t stream) {
  (void)in_sizes; (void)n_in; (void)out_size; (void)ws_size;
  const float* query = (const float*)d_in[0];
  const float* key   = (const float*)d_in[1];
  const float* value = (const float*)d_in[2];
  const float* Wq    = (const float*)d_in[3];
  const float* bq    = (const float*)d_in[4];
  const float* Wk    = (const float*)d_in[5];
  const float* bk    = (const float*)d_in[6];
  const float* Wv    = (const float*)d_in[7];
  const float* bv    = (const float*)d_in[8];
  const float* Wo    = (const float*)d_in[9];
  const float* bo    = (const float*)d_in[10];

  float* out   = (float*)d_out;
  float* wattn = out + (size_t)NTOK*EDIM;

  f16* p    = (f16*)d_ws;
  f16* q16  = p;  p += (size_t)NTOK*EDIM;    // k16, v16 follow contiguously
  f16* k16  = p;  p += (size_t)NTOK*EDIM;
  f16* v16  = p;  p += (size_t)NTOK*EDIM;
  f16* wqT  = p;  p += (size_t)EDIM*EDIM;    // packed [3072][2048] starts here
  f16* wkT  = p;  p += (size_t)KVD*EDIM;
  f16* wvT  = p;  p += (size_t)KVD*EDIM;
  f16* woT  = p;  p += (size_t)EDIM*EDIM;
  f16* QKVp = p;  p += (size_t)NTOK*QKVN;
  f16* Vt   = p;  p += (size_t)NTOK*KVD;
  f16* AO   = p;  p += (size_t)NTOK*EDIM;
  (void)k16; (void)v16;

  // prep: cvt3 (24576 blocks) + tconv EDIMxEDIM x2 (8192) + tconv EDIMxKVD x2 (2048)
  k_prep<<<34816, 256, 0, stream>>>(query, key, value, q16,
                                    Wq, Wo, wqT, woT, Wk, Wv, wkT, wvT);

  k_gemm_qkv<<<dim3(QKVN/128, NTOK/128), 256, 0, stream>>>(
      q16, wqT, bq, bk, bv, QKVp);

  k_trv<<<dim3(NB*NHKV, SEQ/64), 256, 0, stream>>>(QKVp, Vt);

  k_attn<<<NB*NHQ*(SEQ/64), 256, 0, stream>>>(QKVp, Vt, wattn, AO);

  k_gemm<<<dim3(EDIM/128, NTOK/128), 256, 0, stream>>>(
      AO, woT, bo, out, NTOK, EDIM, EDIM);
}

// Round 10
// 489.728 us; speedup vs baseline: 1.2184x; 1.2184x over previous
//
#include <hip/hip_runtime.h>
#include <stdint.h>

typedef _Float16 f16;
typedef _Float16 f16x8 __attribute__((ext_vector_type(8)));
typedef _Float16 f16x4 __attribute__((ext_vector_type(4)));
typedef float    f32x4 __attribute__((ext_vector_type(4)));

#define SEQ   2048
#define EDIM  2048
#define NHQ   32
#define NHKV  8
#define DHEAD 64
#define KVD   512
#define NB    2
#define NTOK  (NB*SEQ)
#define QKVN  3072              // packed Q|K|V projection width
#define SCALE 0.1803368801111204f   // log2(e)/8

__device__ __forceinline__ f32x4 mfma16(f16x8 a, f16x8 b, f32x4 c) {
  return __builtin_amdgcn_mfma_f32_16x16x32_f16(a, b, c, 0, 0, 0);
}

__device__ __forceinline__ void gload_lds16(const void* g, void* l) {
  __builtin_amdgcn_global_load_lds(
      (const __attribute__((address_space(1))) void*)g,
      (__attribute__((address_space(3))) void*)l, 16, 0, 0);
}

// ---------------- fused prep: cvt3 (blocks 0..24575) + tconv EDIMxEDIM pair
// (24576..32767) + tconv EDIMxKVD pair (32768..34815), one launch ----------------
__global__ __launch_bounds__(256) void k_prep(
    const float* __restrict__ q, const float* __restrict__ k,
    const float* __restrict__ v, f16* __restrict__ d3,
    const float* __restrict__ Wq, const float* __restrict__ Wo,
    f16* __restrict__ wqT, f16* __restrict__ woT,
    const float* __restrict__ Wk, const float* __restrict__ Wv,
    f16* __restrict__ wkT, f16* __restrict__ wvT)
{
  __shared__ float t[32][33];
  const int blk = blockIdx.x;
  if (blk < 24576) {                       // convert q,k,v f32 -> f16
    int i = blk * 256 + threadIdx.x;
    int tt = i >> 21, j = i & ((1 << 21) - 1);
    const float* s = tt == 0 ? q : (tt == 1 ? k : v);
    float4 vv = reinterpret_cast<const float4*>(s)[j];
    f16x4 h;
    h[0] = (f16)vv.x; h[1] = (f16)vv.y; h[2] = (f16)vv.z; h[3] = (f16)vv.w;
    reinterpret_cast<f16x4*>(d3)[i] = h;
    return;
  }
  const float* s; f16* d; int C, tr, tc;
  if (blk < 32768) {                       // Wq / Wo transpose-convert
    int bb = blk - 24576;
    int z = bb >> 12; bb &= 4095;
    tr = bb >> 6; tc = bb & 63;
    s = z ? Wo : Wq; d = z ? woT : wqT; C = EDIM;
  } else {                                 // Wk / Wv transpose-convert
    int bb = blk - 32768;
    int z = bb >> 10; bb &= 1023;
    tr = bb >> 4; tc = bb & 15;
    s = z ? Wv : Wk; d = z ? wvT : wkT; C = KVD;
  }
  int lr = threadIdx.x >> 3, lc = (threadIdx.x & 7) << 2;
  float4 vv = *reinterpret_cast<const float4*>(&s[(size_t)(tr*32+lr)*C + tc*32 + lc]);
  t[lr][lc+0] = vv.x; t[lr][lc+1] = vv.y; t[lr][lc+2] = vv.z; t[lr][lc+3] = vv.w;
  __syncthreads();
  f16x4 h;
  h[0] = (f16)t[lc+0][lr];
  h[1] = (f16)t[lc+1][lr];
  h[2] = (f16)t[lc+2][lr];
  h[3] = (f16)t[lc+3][lr];
  *reinterpret_cast<f16x4*>(&d[(size_t)(tc*32+lr)*EDIM + tr*32 + lc]) = h;
}

// ------- transpose V slice of QKVp: [4096][3072](cols 2560+) -> Vt [16][64][2048] -------
__global__ __launch_bounds__(256) void k_trv(const f16* __restrict__ qkv,
                                             f16* __restrict__ dst) {
  __shared__ f16 t[64][68];
  int bh = blockIdx.x;            // b*8 + hkv
  int st = blockIdx.y;            // s tile (64)
  int b = bh >> 3, h = bh & 7;
  #pragma unroll
  for (int i = 0; i < 4; ++i) {
    int sl = i*16 + (threadIdx.x >> 4);
    int d4 = (threadIdx.x & 15) * 4;
    *(f16x4*)&t[sl][d4] =
        *(const f16x4*)&qkv[(size_t)(b*SEQ + st*64 + sl)*QKVN + 2560 + h*DHEAD + d4];
  }
  __syncthreads();
  #pragma unroll
  for (int i = 0; i < 4; ++i) {
    int dl = i*16 + (threadIdx.x >> 4);
    int s4 = (threadIdx.x & 15) * 4;
    f16x4 v;
    v[0] = t[s4+0][dl]; v[1] = t[s4+1][dl]; v[2] = t[s4+2][dl]; v[3] = t[s4+3][dl];
    *(f16x4*)&dst[(size_t)(bh*DHEAD + dl)*SEQ + st*64 + s4] = v;
  }
}

// ------- fused QKV projection: QKVp[4096][3072] = [q16|k16|v16] @ Wt^T + bias -------
__global__ __launch_bounds__(256) void k_gemm_qkv(
    const f16* __restrict__ Abase,   // q16; k16,v16 follow contiguously
    const f16* __restrict__ Wt,
    const float* __restrict__ bq, const float* __restrict__ bk,
    const float* __restrict__ bv,
    f16* __restrict__ Cout)
{
  const int flat = blockIdx.y * gridDim.x + blockIdx.x;   // 0..767
  const int xcd = flat & 7, idx = flat >> 3;              // idx 0..95
  const int tn = xcd*3 + (idx % 3);
  const int tm = idx / 3;
  const int sel = (tn >= 16) + (tn >= 20);
  const f16* A = Abase + (size_t)sel*NTOK*EDIM;
  const float* bias = sel == 0 ? bq : (sel == 1 ? bk : bv);
  const int coff = sel == 0 ? 0 : (sel == 1 ? 2048 : 2560);

  __shared__ f16 sA[128*64];
  __shared__ f16 sB[128*64];
  const int tid  = threadIdx.x;
  const int lane = tid & 63, wv = tid >> 6;
  const int wm = wv >> 1, wn = wv & 1;
  const int l15 = lane & 15, lhi = lane >> 4;

  const f32x4 zz = {0.f, 0.f, 0.f, 0.f};
  f32x4 acc[4][4];
  #pragma unroll
  for (int m = 0; m < 4; ++m)
    #pragma unroll
    for (int n = 0; n < 4; ++n) acc[m][n] = zz;

  const f16* gsrc[8];
  f16* ldst[8];
  #pragma unroll
  for (int i = 0; i < 8; ++i) {
    int u = wv*8 + i;
    int r  = (u & 15)*8 + (lane >> 3);
    int cb = ((lane & 7) << 4) ^ ((r & 7) << 4);
    if (u < 16) {
      gsrc[i] = A  + (size_t)(tm*128 + r)*EDIM + (cb >> 1);
      ldst[i] = sA + u*512;
    } else {
      gsrc[i] = Wt + (size_t)(tn*128 + r)*EDIM + (cb >> 1);
      ldst[i] = sB + (u - 16)*512;
    }
  }

  int aoff[2][4], boff[2][4];
  #pragma unroll
  for (int ks = 0; ks < 2; ++ks)
    #pragma unroll
    for (int m = 0; m < 4; ++m) {
      int ra = wm*64 + m*16 + l15;
      aoff[ks][m] = ra*128 + ((ks*64 + (lhi << 4)) ^ ((ra & 7) << 4));
      int rb = wn*64 + m*16 + l15;
      boff[ks][m] = rb*128 + ((ks*64 + (lhi << 4)) ^ ((rb & 7) << 4));
    }

  for (int kb = 0; kb < EDIM/64; ++kb) {
    #pragma unroll
    for (int i = 0; i < 8; ++i)
      gload_lds16(gsrc[i] + kb*64, ldst[i]);
    __syncthreads();
    #pragma unroll
    for (int ks = 0; ks < 2; ++ks) {
      f16x8 af[4], bf[4];
      #pragma unroll
      for (int m = 0; m < 4; ++m)
        af[m] = *(const f16x8*)((const char*)sA + aoff[ks][m]);
      #pragma unroll
      for (int n = 0; n < 4; ++n)
        bf[n] = *(const f16x8*)((const char*)sB + boff[ks][n]);
      #pragma unroll
      for (int m = 0; m < 4; ++m)
        #pragma unroll
        for (int n = 0; n < 4; ++n)
          acc[m][n] = mfma16(af[m], bf[n], acc[m][n]);
    }
    __syncthreads();
  }

  float bcol[4];
  #pragma unroll
  for (int n = 0; n < 4; ++n)
    bcol[n] = bias[tn*128 + wn*64 + n*16 + l15 - coff];
  #pragma unroll
  for (int m = 0; m < 4; ++m)
    #pragma unroll
    for (int n = 0; n < 4; ++n)
      #pragma unroll
      for (int r = 0; r < 4; ++r) {
        int row = tm*128 + wm*64 + m*16 + lhi*4 + r;
        int col = tn*128 + wn*64 + n*16 + l15;
        Cout[(size_t)row*QKVN + col] = (f16)(acc[m][n][r] + bcol[n]);
      }
}

// ---------------- GEMM (out-proj): C[M,N] f32 = A[M,K] * Bt[N,K]^T + bias ----------------
__global__ __launch_bounds__(256) void k_gemm(
    const f16* __restrict__ A, const f16* __restrict__ Bt,
    const float* __restrict__ bias, float* __restrict__ Cout,
    int M, int N, int K)
{
  const int flat = blockIdx.y * gridDim.x + blockIdx.x;   // 0..511
  const int xcd = flat & 7, idx = flat >> 3;              // idx 0..63
  const int tn = xcd*2 + (idx & 1);
  const int tm = idx >> 1;

  __shared__ f16 sA[128*64];
  __shared__ f16 sB[128*64];
  const int tid  = threadIdx.x;
  const int lane = tid & 63, wv = tid >> 6;
  const int wm = wv >> 1, wn = wv & 1;
  const int l15 = lane & 15, lhi = lane >> 4;

  const f32x4 zz = {0.f, 0.f, 0.f, 0.f};
  f32x4 acc[4][4];
  #pragma unroll
  for (int m = 0; m < 4; ++m)
    #pragma unroll
    for (int n = 0; n < 4; ++n) acc[m][n] = zz;

  const f16* gsrc[8];
  f16* ldst[8];
  #pragma unroll
  for (int i = 0; i < 8; ++i) {
    int u = wv*8 + i;
    int r  = (u & 15)*8 + (lane >> 3);
    int cb = ((lane & 7) << 4) ^ ((r & 7) << 4);
    if (u < 16) {
      gsrc[i] = A  + (size_t)(tm*128 + r)*K + (cb >> 1);
      ldst[i] = sA + u*512;
    } else {
      gsrc[i] = Bt + (size_t)(tn*128 + r)*K + (cb >> 1);
      ldst[i] = sB + (u - 16)*512;
    }
  }

  int aoff[2][4], boff[2][4];
  #pragma unroll
  for (int ks = 0; ks < 2; ++ks)
    #pragma unroll
    for (int m = 0; m < 4; ++m) {
      int ra = wm*64 + m*16 + l15;
      aoff[ks][m] = ra*128 + ((ks*64 + (lhi << 4)) ^ ((ra & 7) << 4));
      int rb = wn*64 + m*16 + l15;
      boff[ks][m] = rb*128 + ((ks*64 + (lhi << 4)) ^ ((rb & 7) << 4));
    }

  const int nkb = K >> 6;
  for (int kb = 0; kb < nkb; ++kb) {
    #pragma unroll
    for (int i = 0; i < 8; ++i)
      gload_lds16(gsrc[i] + kb*64, ldst[i]);
    __syncthreads();
    #pragma unroll
    for (int ks = 0; ks < 2; ++ks) {
      f16x8 af[4], bf[4];
      #pragma unroll
      for (int m = 0; m < 4; ++m)
        af[m] = *(const f16x8*)((const char*)sA + aoff[ks][m]);
      #pragma unroll
      for (int n = 0; n < 4; ++n)
        bf[n] = *(const f16x8*)((const char*)sB + boff[ks][n]);
      #pragma unroll
      for (int m = 0; m < 4; ++m)
        #pragma unroll
        for (int n = 0; n < 4; ++n)
          acc[m][n] = mfma16(af[m], bf[n], acc[m][n]);
    }
    __syncthreads();
  }

  float bcol[4];
  #pragma unroll
  for (int n = 0; n < 4; ++n)
    bcol[n] = bias[tn*128 + wn*64 + n*16 + l15];
  #pragma unroll
  for (int m = 0; m < 4; ++m)
    #pragma unroll
    for (int n = 0; n < 4; ++n)
      #pragma unroll
      for (int r = 0; r < 4; ++r) {
        int row = tm*128 + wm*64 + m*16 + lhi*4 + r;
        int col = tn*128 + wn*64 + n*16 + l15;
        Cout[(size_t)row*N + col] = acc[m][n][r] + bcol[n];
      }
}

// ---------------- fused GQA attention ----------------
// Round-8 structure; pass A widened to 128-k rounds over a unified 4-slot
// LDS pool (sKV) -> barrier count halves (32 -> 16). Pass B identical
// (slots sKV[0..1] = K dbuf, sKV[2..3] = V dbuf).
__global__ __launch_bounds__(256) void k_attn(
    const f16* __restrict__ QKV,  // [4096][3072]: Q | K | V
    const f16* __restrict__ Vt,   // [16][64][2048]
    float* __restrict__ wout,     // [2][32][2048][2048]
    f16* __restrict__ AO)         // [4096][2048]
{
  __shared__ f16 sKV[4][64*64];   // 32 KB: 4 x 8 KB slots
  __shared__ f16 sW[4][16*64];    // 8 KB, per-wave w tile
  const int tid = threadIdx.x, lane = tid & 63, wv = tid >> 6;
  const int bid = (blockIdx.x & 7) * 256 + (blockIdx.x >> 3);  // 2048 % 8 == 0
  const int b = bid >> 10, h = (bid >> 5) & 31, qb = bid & 31;
  const int hk = h >> 2;
  const int l15 = lane & 15, lhi = lane >> 4;
  const int rloc = (lane >> 3) & 7, chk = lane & 7;
  const int csw = (chk ^ rloc) * 8;
  const int sw  = (l15 & 7) << 4;
  const int qrow0 = qb*64 + wv*16;
  const f32x4 zz = {0.f, 0.f, 0.f, 0.f};

  f16x8 qf[2];
  #pragma unroll
  for (int ks = 0; ks < 2; ++ks)
    qf[ks] = *(const f16x8*)&QKV[(size_t)(b*SEQ + qrow0 + l15)*QKVN
                                 + h*DHEAD + ks*32 + lhi*8];

  const f16* Kb = QKV + 2048 + (size_t)(b*SEQ)*QKVN + hk*DHEAD;
  const f16* Vb = Vt + (size_t)((b*NHKV + hk)*DHEAD)*SEQ;

  // ---- pass A: denominator, 128-k per sync round (4 slots, 2 live pairs) ----
  float lsum = 0.f;
  {
    #pragma unroll
    for (int i = 0; i < 2; ++i) {
      int u = wv*2 + i;
      gload_lds16(Kb + (size_t)(u*8 + rloc)*QKVN + csw,        &sKV[0][u*512]);
      gload_lds16(Kb + (size_t)(64 + u*8 + rloc)*QKVN + csw,   &sKV[1][u*512]);
    }
    __syncthreads();
    int pr = 0;
    for (int kb = 0; kb < SEQ/128; ++kb) {
      if (kb < SEQ/128 - 1) {
        #pragma unroll
        for (int i = 0; i < 2; ++i) {
          int u = wv*2 + i;
          gload_lds16(Kb + (size_t)((kb+1)*128 + u*8 + rloc)*QKVN + csw,
                      &sKV[(pr^1)*2][u*512]);
          gload_lds16(Kb + (size_t)((kb+1)*128 + 64 + u*8 + rloc)*QKVN + csw,
                      &sKV[(pr^1)*2+1][u*512]);
        }
      }
      #pragma unroll
      for (int kt = 0; kt < 8; ++kt) {
        const char* kbase = (const char*)&sKV[pr*2 + (kt >> 2)][0]
                            + ((kt & 3)*16 + l15)*128;
        f16x8 kf0 = *(const f16x8*)(kbase + ((lhi*16) ^ sw));
        f16x8 kf1 = *(const f16x8*)(kbase + ((64 + lhi*16) ^ sw));
        f32x4 s = zz;
        s = mfma16(kf0, qf[0], s);       // swapped: row=k, col=q(l15)
        s = mfma16(kf1, qf[1], s);
        #pragma unroll
        for (int r = 0; r < 4; ++r)
          lsum += __builtin_amdgcn_exp2f(s[r] * SCALE);
      }
      __syncthreads();
      pr ^= 1;
    }
  }
  float den = lsum;
  den += __shfl_xor(den, 16);
  den += __shfl_xor(den, 32);
  const float rinv = __builtin_amdgcn_rcpf(den);   // denominator for q = l15

  // ---- pass B (round-8 structure; K = sKV[buf], V = sKV[2+buf]) ----
  f32x4 o[4];
  #pragma unroll
  for (int dt = 0; dt < 4; ++dt) o[dt] = zz;

  f16* swv = &sW[wv][0];
  float* wrow = wout + (size_t)((b*NHQ + h)*SEQ + qrow0)*SEQ;

  {
    #pragma unroll
    for (int i = 0; i < 2; ++i) {
      int u = wv*2 + i;
      gload_lds16(Kb + (size_t)(u*8 + rloc)*QKVN + csw, &sKV[0][u*512]);
      gload_lds16(Vb + (size_t)(u*8 + rloc)*SEQ + csw,  &sKV[2][u*512]);
    }
    __syncthreads();
    int buf = 0;
    for (int kb = 0; kb < SEQ/64; ++kb) {
      if (kb < SEQ/64 - 1) {
        #pragma unroll
        for (int i = 0; i < 2; ++i) {
          int u = wv*2 + i;
          gload_lds16(Kb + (size_t)((kb+1)*64 + u*8 + rloc)*QKVN + csw,
                      &sKV[buf^1][u*512]);
          gload_lds16(Vb + (size_t)(u*8 + rloc)*SEQ + (kb+1)*64 + csw,
                      &sKV[2+(buf^1)][u*512]);
        }
      }
      __builtin_amdgcn_sched_barrier(0);   // pin: loads issue before the stores below
      #pragma unroll
      for (int kt = 0; kt < 4; ++kt) {
        const char* kbase = (const char*)&sKV[buf][0] + (kt*16 + l15)*128;
        f16x8 kf0 = *(const f16x8*)(kbase + ((lhi*16) ^ sw));
        f16x8 kf1 = *(const f16x8*)(kbase + ((64 + lhi*16) ^ sw));
        f32x4 s = zz;
        s = mfma16(kf0, qf[0], s);
        s = mfma16(kf1, qf[1], s);
        f32x4 wvec;
        f16x4 wh;
        #pragma unroll
        for (int r = 0; r < 4; ++r) {
          float wgt = __builtin_amdgcn_exp2f(s[r] * SCALE) * rinv;
          wvec[r] = wgt;
          wh[r] = (f16)wgt;
        }
        __builtin_nontemporal_store(wvec,
            (f32x4*)(wrow + (size_t)l15*SEQ + kb*64 + kt*16 + lhi*4));
        *(f16x4*)((char*)swv + l15*128 + ((kt*32 + lhi*8) ^ sw)) = wh;
      }
      #pragma unroll
      for (int ks = 0; ks < 2; ++ks) {
        f16x8 af = *(const f16x8*)((const char*)swv + l15*128 + ((ks*64 + lhi*16) ^ sw));
        #pragma unroll
        for (int dt = 0; dt < 4; ++dt) {
          const char* vbase = (const char*)&sKV[2+buf][0] + (dt*16 + l15)*128;
          f16x8 vf = *(const f16x8*)(vbase + ((ks*64 + lhi*16) ^ sw));
          o[dt] = mfma16(af, vf, o[dt]);
        }
      }
      asm volatile("s_waitcnt vmcnt(4)" ::: "memory");
      __builtin_amdgcn_s_barrier();
      __builtin_amdgcn_sched_barrier(0);
      buf ^= 1;
    }
  }

  #pragma unroll
  for (int dt = 0; dt < 4; ++dt)
    #pragma unroll
    for (int r = 0; r < 4; ++r)
      AO[(size_t)(b*SEQ + qrow0 + lhi*4 + r)*EDIM + h*DHEAD + dt*16 + l15]
          = (f16)o[dt][r];
}

// ---------------- launch ----------------
extern "C" void kernel_launch(void* const* d_in, const int* in_sizes, int n_in,
                              void* d_out, int out_size, void* d_ws, size_t ws_size,
                              hipStream_t stream) {
  (void)in_sizes; (void)n_in; (void)out_size; (void)ws_size;
  const float* query = (const float*)d_in[0];
  const float* key   = (const float*)d_in[1];
  const float* value = (const float*)d_in[2];
  const float* Wq    = (const float*)d_in[3];
  const float* bq    = (const float*)d_in[4];
  const float* Wk    = (const float*)d_in[5];
  const float* bk    = (const float*)d_in[6];
  const float* Wv    = (const float*)d_in[7];
  const float* bv    = (const float*)d_in[8];
  const float* Wo    = (const float*)d_in[9];
  const float* bo    = (const float*)d_in[10];

  float* out   = (float*)d_out;
  float* wattn = out + (size_t)NTOK*EDIM;

  f16* p    = (f16*)d_ws;
  f16* q16  = p;  p += (size_t)NTOK*EDIM;    // k16, v16 follow contiguously
  f16* k16  = p;  p += (size_t)NTOK*EDIM;
  f16* v16  = p;  p += (size_t)NTOK*EDIM;
  f16* wqT  = p;  p += (size_t)EDIM*EDIM;    // packed [3072][2048] starts here
  f16* wkT  = p;  p += (size_t)KVD*EDIM;
  f16* wvT  = p;  p += (size_t)KVD*EDIM;
  f16* woT  = p;  p += (size_t)EDIM*EDIM;
  f16* QKVp = p;  p += (size_t)NTOK*QKVN;
  f16* Vt   = p;  p += (size_t)NTOK*KVD;
  f16* AO   = p;  p += (size_t)NTOK*EDIM;
  (void)k16; (void)v16;

  // prep: cvt3 (24576 blocks) + tconv EDIMxEDIM x2 (8192) + tconv EDIMxKVD x2 (2048)
  k_prep<<<34816, 256, 0, stream>>>(query, key, value, q16,
                                    Wq, Wo, wqT, woT, Wk, Wv, wkT, wvT);

  k_gemm_qkv<<<dim3(QKVN/128, NTOK/128), 256, 0, stream>>>(
      q16, wqT, bq, bk, bv, QKVp);

  k_trv<<<dim3(NB*NHKV, SEQ/64), 256, 0, stream>>>(QKVp, Vt);

  k_attn<<<NB*NHQ*(SEQ/64), 256, 0, stream>>>(QKVp, Vt, wattn, AO);

  k_gemm<<<dim3(EDIM/128, NTOK/128), 256, 0, stream>>>(
      AO, woT, bo, out, NTOK, EDIM, EDIM);
}

// Round 11
// 475.396 us; speedup vs baseline: 1.2551x; 1.0301x over previous
//
#include <hip/hip_runtime.h>
#include <stdint.h>

typedef _Float16 f16;
typedef _Float16 f16x8 __attribute__((ext_vector_type(8)));
typedef _Float16 f16x4 __attribute__((ext_vector_type(4)));
typedef float    f32x4 __attribute__((ext_vector_type(4)));

#define SEQ   2048
#define EDIM  2048
#define NHQ   32
#define NHKV  8
#define DHEAD 64
#define KVD   512
#define NB    2
#define NTOK  (NB*SEQ)
#define QKVN  3072              // packed Q|K|V projection width
#define SCALE 0.1803368801111204f   // log2(e)/8

__device__ __forceinline__ f32x4 mfma16(f16x8 a, f16x8 b, f32x4 c) {
  return __builtin_amdgcn_mfma_f32_16x16x32_f16(a, b, c, 0, 0, 0);
}

__device__ __forceinline__ void gload_lds16(const void* g, void* l) {
  __builtin_amdgcn_global_load_lds(
      (const __attribute__((address_space(1))) void*)g,
      (__attribute__((address_space(3))) void*)l, 16, 0, 0);
}

// ---------------- fused prep: cvt3 (blocks 0..24575) + tconv EDIMxEDIM pair
// (24576..32767) + tconv EDIMxKVD pair (32768..34815), one launch ----------------
__global__ __launch_bounds__(256) void k_prep(
    const float* __restrict__ q, const float* __restrict__ k,
    const float* __restrict__ v, f16* __restrict__ d3,
    const float* __restrict__ Wq, const float* __restrict__ Wo,
    f16* __restrict__ wqT, f16* __restrict__ woT,
    const float* __restrict__ Wk, const float* __restrict__ Wv,
    f16* __restrict__ wkT, f16* __restrict__ wvT)
{
  __shared__ float t[32][33];
  const int blk = blockIdx.x;
  if (blk < 24576) {                       // convert q,k,v f32 -> f16
    int i = blk * 256 + threadIdx.x;
    int tt = i >> 21, j = i & ((1 << 21) - 1);
    const float* s = tt == 0 ? q : (tt == 1 ? k : v);
    float4 vv = reinterpret_cast<const float4*>(s)[j];
    f16x4 h;
    h[0] = (f16)vv.x; h[1] = (f16)vv.y; h[2] = (f16)vv.z; h[3] = (f16)vv.w;
    reinterpret_cast<f16x4*>(d3)[i] = h;
    return;
  }
  const float* s; f16* d; int C, tr, tc;
  if (blk < 32768) {                       // Wq / Wo transpose-convert
    int bb = blk - 24576;
    int z = bb >> 12; bb &= 4095;
    tr = bb >> 6; tc = bb & 63;
    s = z ? Wo : Wq; d = z ? woT : wqT; C = EDIM;
  } else {                                 // Wk / Wv transpose-convert
    int bb = blk - 32768;
    int z = bb >> 10; bb &= 1023;
    tr = bb >> 4; tc = bb & 15;
    s = z ? Wv : Wk; d = z ? wvT : wkT; C = KVD;
  }
  int lr = threadIdx.x >> 3, lc = (threadIdx.x & 7) << 2;
  float4 vv = *reinterpret_cast<const float4*>(&s[(size_t)(tr*32+lr)*C + tc*32 + lc]);
  t[lr][lc+0] = vv.x; t[lr][lc+1] = vv.y; t[lr][lc+2] = vv.z; t[lr][lc+3] = vv.w;
  __syncthreads();
  f16x4 h;
  h[0] = (f16)t[lc+0][lr];
  h[1] = (f16)t[lc+1][lr];
  h[2] = (f16)t[lc+2][lr];
  h[3] = (f16)t[lc+3][lr];
  *reinterpret_cast<f16x4*>(&d[(size_t)(tc*32+lr)*EDIM + tr*32 + lc]) = h;
}

// ------- transpose V slice of QKVp: [4096][3072](cols 2560+) -> Vt [16][64][2048] -------
__global__ __launch_bounds__(256) void k_trv(const f16* __restrict__ qkv,
                                             f16* __restrict__ dst) {
  __shared__ f16 t[64][68];
  int bh = blockIdx.x;            // b*8 + hkv
  int st = blockIdx.y;            // s tile (64)
  int b = bh >> 3, h = bh & 7;
  #pragma unroll
  for (int i = 0; i < 4; ++i) {
    int sl = i*16 + (threadIdx.x >> 4);
    int d4 = (threadIdx.x & 15) * 4;
    *(f16x4*)&t[sl][d4] =
        *(const f16x4*)&qkv[(size_t)(b*SEQ + st*64 + sl)*QKVN + 2560 + h*DHEAD + d4];
  }
  __syncthreads();
  #pragma unroll
  for (int i = 0; i < 4; ++i) {
    int dl = i*16 + (threadIdx.x >> 4);
    int s4 = (threadIdx.x & 15) * 4;
    f16x4 v;
    v[0] = t[s4+0][dl]; v[1] = t[s4+1][dl]; v[2] = t[s4+2][dl]; v[3] = t[s4+3][dl];
    *(f16x4*)&dst[(size_t)(bh*DHEAD + dl)*SEQ + st*64 + s4] = v;
  }
}

// ------- fused QKV projection: QKVp[4096][3072] = [q16|k16|v16] @ Wt^T + bias -------
__global__ __launch_bounds__(256) void k_gemm_qkv(
    const f16* __restrict__ Abase,   // q16; k16,v16 follow contiguously
    const f16* __restrict__ Wt,
    const float* __restrict__ bq, const float* __restrict__ bk,
    const float* __restrict__ bv,
    f16* __restrict__ Cout)
{
  const int flat = blockIdx.y * gridDim.x + blockIdx.x;   // 0..767
  const int xcd = flat & 7, idx = flat >> 3;              // idx 0..95
  const int tn = xcd*3 + (idx % 3);
  const int tm = idx / 3;
  const int sel = (tn >= 16) + (tn >= 20);
  const f16* A = Abase + (size_t)sel*NTOK*EDIM;
  const float* bias = sel == 0 ? bq : (sel == 1 ? bk : bv);
  const int coff = sel == 0 ? 0 : (sel == 1 ? 2048 : 2560);

  __shared__ f16 sA[128*64];
  __shared__ f16 sB[128*64];
  const int tid  = threadIdx.x;
  const int lane = tid & 63, wv = tid >> 6;
  const int wm = wv >> 1, wn = wv & 1;
  const int l15 = lane & 15, lhi = lane >> 4;

  const f32x4 zz = {0.f, 0.f, 0.f, 0.f};
  f32x4 acc[4][4];
  #pragma unroll
  for (int m = 0; m < 4; ++m)
    #pragma unroll
    for (int n = 0; n < 4; ++n) acc[m][n] = zz;

  const f16* gsrc[8];
  f16* ldst[8];
  #pragma unroll
  for (int i = 0; i < 8; ++i) {
    int u = wv*8 + i;
    int r  = (u & 15)*8 + (lane >> 3);
    int cb = ((lane & 7) << 4) ^ ((r & 7) << 4);
    if (u < 16) {
      gsrc[i] = A  + (size_t)(tm*128 + r)*EDIM + (cb >> 1);
      ldst[i] = sA + u*512;
    } else {
      gsrc[i] = Wt + (size_t)(tn*128 + r)*EDIM + (cb >> 1);
      ldst[i] = sB + (u - 16)*512;
    }
  }

  int aoff[2][4], boff[2][4];
  #pragma unroll
  for (int ks = 0; ks < 2; ++ks)
    #pragma unroll
    for (int m = 0; m < 4; ++m) {
      int ra = wm*64 + m*16 + l15;
      aoff[ks][m] = ra*128 + ((ks*64 + (lhi << 4)) ^ ((ra & 7) << 4));
      int rb = wn*64 + m*16 + l15;
      boff[ks][m] = rb*128 + ((ks*64 + (lhi << 4)) ^ ((rb & 7) << 4));
    }

  for (int kb = 0; kb < EDIM/64; ++kb) {
    #pragma unroll
    for (int i = 0; i < 8; ++i)
      gload_lds16(gsrc[i] + kb*64, ldst[i]);
    __syncthreads();
    #pragma unroll
    for (int ks = 0; ks < 2; ++ks) {
      f16x8 af[4], bf[4];
      #pragma unroll
      for (int m = 0; m < 4; ++m)
        af[m] = *(const f16x8*)((const char*)sA + aoff[ks][m]);
      #pragma unroll
      for (int n = 0; n < 4; ++n)
        bf[n] = *(const f16x8*)((const char*)sB + boff[ks][n]);
      #pragma unroll
      for (int m = 0; m < 4; ++m)
        #pragma unroll
        for (int n = 0; n < 4; ++n)
          acc[m][n] = mfma16(af[m], bf[n], acc[m][n]);
    }
    __syncthreads();
  }

  float bcol[4];
  #pragma unroll
  for (int n = 0; n < 4; ++n)
    bcol[n] = bias[tn*128 + wn*64 + n*16 + l15 - coff];
  #pragma unroll
  for (int m = 0; m < 4; ++m)
    #pragma unroll
    for (int n = 0; n < 4; ++n)
      #pragma unroll
      for (int r = 0; r < 4; ++r) {
        int row = tm*128 + wm*64 + m*16 + lhi*4 + r;
        int col = tn*128 + wn*64 + n*16 + l15;
        Cout[(size_t)row*QKVN + col] = (f16)(acc[m][n][r] + bcol[n]);
      }
}

// ---------------- GEMM (out-proj): C[M,N] f32 = A[M,K] * Bt[N,K]^T + bias ----------------
// C is zero-reuse (final output): nontemporal stores keep L2 for A/B panels.
__global__ __launch_bounds__(256) void k_gemm(
    const f16* __restrict__ A, const f16* __restrict__ Bt,
    const float* __restrict__ bias, float* __restrict__ Cout,
    int M, int N, int K)
{
  const int flat = blockIdx.y * gridDim.x + blockIdx.x;   // 0..511
  const int xcd = flat & 7, idx = flat >> 3;              // idx 0..63
  const int tn = xcd*2 + (idx & 1);
  const int tm = idx >> 1;

  __shared__ f16 sA[128*64];
  __shared__ f16 sB[128*64];
  const int tid  = threadIdx.x;
  const int lane = tid & 63, wv = tid >> 6;
  const int wm = wv >> 1, wn = wv & 1;
  const int l15 = lane & 15, lhi = lane >> 4;

  const f32x4 zz = {0.f, 0.f, 0.f, 0.f};
  f32x4 acc[4][4];
  #pragma unroll
  for (int m = 0; m < 4; ++m)
    #pragma unroll
    for (int n = 0; n < 4; ++n) acc[m][n] = zz;

  const f16* gsrc[8];
  f16* ldst[8];
  #pragma unroll
  for (int i = 0; i < 8; ++i) {
    int u = wv*8 + i;
    int r  = (u & 15)*8 + (lane >> 3);
    int cb = ((lane & 7) << 4) ^ ((r & 7) << 4);
    if (u < 16) {
      gsrc[i] = A  + (size_t)(tm*128 + r)*K + (cb >> 1);
      ldst[i] = sA + u*512;
    } else {
      gsrc[i] = Bt + (size_t)(tn*128 + r)*K + (cb >> 1);
      ldst[i] = sB + (u - 16)*512;
    }
  }

  int aoff[2][4], boff[2][4];
  #pragma unroll
  for (int ks = 0; ks < 2; ++ks)
    #pragma unroll
    for (int m = 0; m < 4; ++m) {
      int ra = wm*64 + m*16 + l15;
      aoff[ks][m] = ra*128 + ((ks*64 + (lhi << 4)) ^ ((ra & 7) << 4));
      int rb = wn*64 + m*16 + l15;
      boff[ks][m] = rb*128 + ((ks*64 + (lhi << 4)) ^ ((rb & 7) << 4));
    }

  const int nkb = K >> 6;
  for (int kb = 0; kb < nkb; ++kb) {
    #pragma unroll
    for (int i = 0; i < 8; ++i)
      gload_lds16(gsrc[i] + kb*64, ldst[i]);
    __syncthreads();
    #pragma unroll
    for (int ks = 0; ks < 2; ++ks) {
      f16x8 af[4], bf[4];
      #pragma unroll
      for (int m = 0; m < 4; ++m)
        af[m] = *(const f16x8*)((const char*)sA + aoff[ks][m]);
      #pragma unroll
      for (int n = 0; n < 4; ++n)
        bf[n] = *(const f16x8*)((const char*)sB + boff[ks][n]);
      #pragma unroll
      for (int m = 0; m < 4; ++m)
        #pragma unroll
        for (int n = 0; n < 4; ++n)
          acc[m][n] = mfma16(af[m], bf[n], acc[m][n]);
    }
    __syncthreads();
  }

  float bcol[4];
  #pragma unroll
  for (int n = 0; n < 4; ++n)
    bcol[n] = bias[tn*128 + wn*64 + n*16 + l15];
  #pragma unroll
  for (int m = 0; m < 4; ++m)
    #pragma unroll
    for (int n = 0; n < 4; ++n)
      #pragma unroll
      for (int r = 0; r < 4; ++r) {
        int row = tm*128 + wm*64 + m*16 + lhi*4 + r;
        int col = tn*128 + wn*64 + n*16 + l15;
        __builtin_nontemporal_store(acc[m][n][r] + bcol[n],
                                    &Cout[(size_t)row*N + col]);
      }
}

// ---------------- fused GQA attention (round-8 structure + T5/exp-fold) ----------------
__global__ __launch_bounds__(256) void k_attn(
    const f16* __restrict__ QKV,  // [4096][3072]: Q | K | V
    const f16* __restrict__ Vt,   // [16][64][2048]
    float* __restrict__ wout,     // [2][32][2048][2048]
    f16* __restrict__ AO)         // [4096][2048]
{
  __shared__ f16 sK[2][64*64];
  __shared__ f16 sV[2][64*64];
  __shared__ f16 sW[4][16*64];
  const int tid = threadIdx.x, lane = tid & 63, wv = tid >> 6;
  const int bid = (blockIdx.x & 7) * 256 + (blockIdx.x >> 3);  // 2048 % 8 == 0
  const int b = bid >> 10, h = (bid >> 5) & 31, qb = bid & 31;
  const int hk = h >> 2;
  const int l15 = lane & 15, lhi = lane >> 4;
  const int rloc = (lane >> 3) & 7, chk = lane & 7;
  const int csw = (chk ^ rloc) * 8;
  const int sw  = (l15 & 7) << 4;
  const int qrow0 = qb*64 + wv*16;
  const f32x4 zz = {0.f, 0.f, 0.f, 0.f};

  f16x8 qf[2];
  #pragma unroll
  for (int ks = 0; ks < 2; ++ks)
    qf[ks] = *(const f16x8*)&QKV[(size_t)(b*SEQ + qrow0 + l15)*QKVN
                                 + h*DHEAD + ks*32 + lhi*8];

  const f16* Kb = QKV + 2048 + (size_t)(b*SEQ)*QKVN + hk*DHEAD;
  const f16* Vb = Vt + (size_t)((b*NHKV + hk)*DHEAD)*SEQ;

  // ---- pass A: denominator (round-8 structure) ----
  float lsum = 0.f;
  {
    #pragma unroll
    for (int i = 0; i < 2; ++i) {
      int u = wv*2 + i;
      gload_lds16(Kb + (size_t)(u*8 + rloc)*QKVN + csw, &sK[0][u*512]);
    }
    __syncthreads();
    int buf = 0;
    for (int kb = 0; kb < SEQ/64; ++kb) {
      if (kb < SEQ/64 - 1) {
        #pragma unroll
        for (int i = 0; i < 2; ++i) {
          int u = wv*2 + i;
          gload_lds16(Kb + (size_t)((kb+1)*64 + u*8 + rloc)*QKVN + csw, &sK[buf^1][u*512]);
        }
      }
      #pragma unroll
      for (int kt = 0; kt < 4; ++kt) {
        const char* kbase = (const char*)&sK[buf][0] + (kt*16 + l15)*128;
        f16x8 kf0 = *(const f16x8*)(kbase + ((lhi*16) ^ sw));
        f16x8 kf1 = *(const f16x8*)(kbase + ((64 + lhi*16) ^ sw));
        __builtin_amdgcn_s_setprio(1);
        f32x4 s = zz;
        s = mfma16(kf0, qf[0], s);
        s = mfma16(kf1, qf[1], s);
        __builtin_amdgcn_s_setprio(0);
        #pragma unroll
        for (int r = 0; r < 4; ++r)
          lsum += __builtin_amdgcn_exp2f(s[r] * SCALE);
      }
      __syncthreads();
      buf ^= 1;
    }
  }
  float den = lsum;
  den += __shfl_xor(den, 16);
  den += __shfl_xor(den, 32);
  const float nldr = -__builtin_amdgcn_logf(den);   // -log2(den), q = l15

  // ---- pass B ----
  f32x4 o[4];
  #pragma unroll
  for (int dt = 0; dt < 4; ++dt) o[dt] = zz;

  f16* swv = &sW[wv][0];
  float* wrow = wout + (size_t)((b*NHQ + h)*SEQ + qrow0)*SEQ;

  {
    #pragma unroll
    for (int i = 0; i < 2; ++i) {
      int u = wv*2 + i;
      gload_lds16(Kb + (size_t)(u*8 + rloc)*QKVN + csw, &sK[0][u*512]);
      gload_lds16(Vb + (size_t)(u*8 + rloc)*SEQ + csw, &sV[0][u*512]);
    }
    __syncthreads();
    int buf = 0;
    for (int kb = 0; kb < SEQ/64; ++kb) {
      if (kb < SEQ/64 - 1) {
        #pragma unroll
        for (int i = 0; i < 2; ++i) {
          int u = wv*2 + i;
          gload_lds16(Kb + (size_t)((kb+1)*64 + u*8 + rloc)*QKVN + csw, &sK[buf^1][u*512]);
          gload_lds16(Vb + (size_t)(u*8 + rloc)*SEQ + (kb+1)*64 + csw, &sV[buf^1][u*512]);
        }
      }
      __builtin_amdgcn_sched_barrier(0);   // pin: loads issue before the stores below
      #pragma unroll
      for (int kt = 0; kt < 4; ++kt) {
        const char* kbase = (const char*)&sK[buf][0] + (kt*16 + l15)*128;
        f16x8 kf0 = *(const f16x8*)(kbase + ((lhi*16) ^ sw));
        f16x8 kf1 = *(const f16x8*)(kbase + ((64 + lhi*16) ^ sw));
        __builtin_amdgcn_s_setprio(1);
        f32x4 s = zz;
        s = mfma16(kf0, qf[0], s);
        s = mfma16(kf1, qf[1], s);
        __builtin_amdgcn_s_setprio(0);
        f32x4 wvec;
        f16x4 wh;
        #pragma unroll
        for (int r = 0; r < 4; ++r) {
          float wgt = __builtin_amdgcn_exp2f(__builtin_fmaf(s[r], SCALE, nldr));
          wvec[r] = wgt;
          wh[r] = (f16)wgt;
        }
        __builtin_nontemporal_store(wvec,
            (f32x4*)(wrow + (size_t)l15*SEQ + kb*64 + kt*16 + lhi*4));
        *(f16x4*)((char*)swv + l15*128 + ((kt*32 + lhi*8) ^ sw)) = wh;
      }
      __builtin_amdgcn_s_setprio(1);
      #pragma unroll
      for (int ks = 0; ks < 2; ++ks) {
        f16x8 af = *(const f16x8*)((const char*)swv + l15*128 + ((ks*64 + lhi*16) ^ sw));
        #pragma unroll
        for (int dt = 0; dt < 4; ++dt) {
          const char* vbase = (const char*)&sV[buf][0] + (dt*16 + l15)*128;
          f16x8 vf = *(const f16x8*)(vbase + ((ks*64 + lhi*16) ^ sw));
          o[dt] = mfma16(af, vf, o[dt]);
        }
      }
      __builtin_amdgcn_s_setprio(0);
      asm volatile("s_waitcnt vmcnt(4)" ::: "memory");
      __builtin_amdgcn_s_barrier();
      __builtin_amdgcn_sched_barrier(0);
      buf ^= 1;
    }
  }

  #pragma unroll
  for (int dt = 0; dt < 4; ++dt)
    #pragma unroll
    for (int r = 0; r < 4; ++r)
      AO[(size_t)(b*SEQ + qrow0 + lhi*4 + r)*EDIM + h*DHEAD + dt*16 + l15]
          = (f16)o[dt][r];
}

// ---------------- launch ----------------
extern "C" void kernel_launch(void* const* d_in, const int* in_sizes, int n_in,
                              void* d_out, int out_size, void* d_ws, size_t ws_size,
                              hipStream_t stream) {
  (void)in_sizes; (void)n_in; (void)out_size; (void)ws_size;
  const float* query = (const float*)d_in[0];
  const float* key   = (const float*)d_in[1];
  const float* value = (const float*)d_in[2];
  const float* Wq    = (const float*)d_in[3];
  const float* bq    = (const float*)d_in[4];
  const float* Wk    = (const float*)d_in[5];
  const float* bk    = (const float*)d_in[6];
  const float* Wv    = (const float*)d_in[7];
  const float* bv    = (const float*)d_in[8];
  const float* Wo    = (const float*)d_in[9];
  const float* bo    = (const float*)d_in[10];

  float* out   = (float*)d_out;
  float* wattn = out + (size_t)NTOK*EDIM;

  f16* p    = (f16*)d_ws;
  f16* q16  = p;  p += (size_t)NTOK*EDIM;    // k16, v16 follow contiguously
  f16* k16  = p;  p += (size_t)NTOK*EDIM;
  f16* v16  = p;  p += (size_t)NTOK*EDIM;
  f16* wqT  = p;  p += (size_t)EDIM*EDIM;    // packed [3072][2048] starts here
  f16* wkT  = p;  p += (size_t)KVD*EDIM;
  f16* wvT  = p;  p += (size_t)KVD*EDIM;
  f16* woT  = p;  p += (size_t)EDIM*EDIM;
  f16* QKVp = p;  p += (size_t)NTOK*QKVN;
  f16* Vt   = p;  p += (size_t)NTOK*KVD;
  f16* AO   = p;  p += (size_t)NTOK*EDIM;
  (void)k16; (void)v16;

  // prep: cvt3 (24576 blocks) + tconv EDIMxEDIM x2 (8192) + tconv EDIMxKVD x2 (2048)
  k_prep<<<34816, 256, 0, stream>>>(query, key, value, q16,
                                    Wq, Wo, wqT, woT, Wk, Wv, wkT, wvT);

  k_gemm_qkv<<<dim3(QKVN/128, NTOK/128), 256, 0, stream>>>(
      q16, wqT, bq, bk, bv, QKVp);

  k_trv<<<dim3(NB*NHKV, SEQ/64), 256, 0, stream>>>(QKVp, Vt);

  k_attn<<<NB*NHQ*(SEQ/64), 256, 0, stream>>>(QKVp, Vt, wattn, AO);

  k_gemm<<<dim3(EDIM/128, NTOK/128), 256, 0, stream>>>(
      AO, woT, bo, out, NTOK, EDIM, EDIM);
}